// Round 9
// baseline (123.291 us; speedup 1.0000x reference)
//
#include <hip/hip_runtime.h>

// SqueezeExcitation: x[32,256,64,64] f32, W1[64,256], b1[64], W2[256,64], b2[256]
// y = x * hardsigmoid( relu( mean_hw(x) @ W1^T + b1 ) @ W2^T + b2 )
// SINGLE kernel, ONE HBM pass over x. 512 blocks x 512 thr, 2/CU co-resident.
// Block owns (batch, 16ch) = 256 KiB = 32 f32x4/thread:
//   12 in registers + 9 in LDS (72 KiB) + 11 re-read (streamed last = L3-MRU).
// r8 lesson: naming registers is NOT enough — x is const/__restrict__, so the
// compiler legally SANK the held loads into phase 2 (VGPR_Count was 64!).
// Fix: opaque asm "+v" barrier after the stream pins the 12 values in VGPRs
// (asm output cannot be rematerialized from memory).
// r7 lesson: no cross-lane ops inside the load stream (deferred reductions).
// r2 lesson: padded per-batch counters only (16 adds each, no contention).

#define SE_B  32
#define SE_C  256
#define SE_SQ 64
#define SE_HW 4096
#define CPB   16
#define TPB   512
#define VPT   32
#define N_REG 12
#define N_LDS 9
#define RDY_STRIDE 32

typedef float f32x4 __attribute__((ext_vector_type(4)));

__device__ __forceinline__ float hsig(float v) {
    return fminf(fmaxf(v * (1.0f / 6.0f) + 0.5f, 0.0f), 1.0f);
}

__global__ __launch_bounds__(TPB, 4) void se_fused_kernel(
    const float* __restrict__ x,
    const float* __restrict__ W1, const float* __restrict__ b1,
    const float* __restrict__ W2, const float* __restrict__ b2,
    float* __restrict__ m, int* __restrict__ ready,
    float* __restrict__ y) {
    const int blk  = blockIdx.x;
    const int b    = blk >> 4;
    const int c0   = (blk & 15) * CPB;
    const int t    = threadIdx.x;
    const int wave = t >> 6;
    const int lane = t & 63;

    __shared__ f32x4 lds[N_LDS * TPB];      // 72 KiB
    __shared__ float partials[CPB * 8];
    __shared__ f32x4 m4_lds[SE_C / 4];
    __shared__ float s_lds[SE_SQ];
    __shared__ float g_lds[CPB];

    const size_t base = ((size_t)b * SE_C + c0) * (SE_HW / 4);
    const f32x4* xv = reinterpret_cast<const f32x4*>(x) + base;
    f32x4*       yv = reinterpret_cast<f32x4*>(y)       + base;

    // ---------------- Phase 1: stream once, named regs/accs ----------------
    f32x4 r0, r1, r2, r3, r4, r5, r6, r7, r8, r9, r10, r11;
    float a0=0,a1=0,a2=0,a3=0,a4=0,a5=0,a6=0,a7=0,
          a8=0,a9=0,a10=0,a11=0,a12=0,a13=0,a14=0,a15=0;

#define SUM4(v) ((v.x + v.y) + (v.z + v.w))
#define ST_REG(k, r, a)  { f32x4 v = xv[(k)*TPB + t]; r = v;                    a += SUM4(v); }
#define ST_LDS(k, a)     { f32x4 v = xv[(k)*TPB + t]; lds[((k)-N_REG)*TPB+t]=v; a += SUM4(v); }
#define ST_NONE(k, a)    { f32x4 v = xv[(k)*TPB + t];                           a += SUM4(v); }

    ST_REG( 0, r0,  a0)  ST_REG( 1, r1,  a0)
    ST_REG( 2, r2,  a1)  ST_REG( 3, r3,  a1)
    ST_REG( 4, r4,  a2)  ST_REG( 5, r5,  a2)
    ST_REG( 6, r6,  a3)  ST_REG( 7, r7,  a3)
    ST_REG( 8, r8,  a4)  ST_REG( 9, r9,  a4)
    ST_REG(10, r10, a5)  ST_REG(11, r11, a5)
    ST_LDS(12, a6)  ST_LDS(13, a6)
    ST_LDS(14, a7)  ST_LDS(15, a7)
    ST_LDS(16, a8)  ST_LDS(17, a8)
    ST_LDS(18, a9)  ST_LDS(19, a9)
    ST_LDS(20, a10)
    ST_NONE(21, a10)
    ST_NONE(22, a11) ST_NONE(23, a11)
    ST_NONE(24, a12) ST_NONE(25, a12)
    ST_NONE(26, a13) ST_NONE(27, a13)
    ST_NONE(28, a14) ST_NONE(29, a14)
    ST_NONE(30, a15) ST_NONE(31, a15)

    // PIN the 12 held values in VGPRs: asm outputs are opaque, so phase 2
    // cannot be "optimized" into reloading x (the r8 failure mode).
    asm volatile("" : "+v"(r0), "+v"(r1), "+v"(r2),  "+v"(r3),
                      "+v"(r4), "+v"(r5), "+v"(r6),  "+v"(r7),
                      "+v"(r8), "+v"(r9), "+v"(r10), "+v"(r11));

    // ---- reductions, once, after the whole stream -------------------------
    {
        float acc[16] = {a0,a1,a2,a3,a4,a5,a6,a7,a8,a9,a10,a11,a12,a13,a14,a15};
#pragma unroll
        for (int j = 0; j < 16; ++j) {
            float p = acc[j];
#pragma unroll
            for (int off = 1; off < 64; off <<= 1) p += __shfl_xor(p, off);
            if (lane == 0) partials[j * 8 + wave] = p;
        }
    }
    __syncthreads();

    if (t < CPB) {
        float s = 0.0f;
#pragma unroll
        for (int w = 0; w < 8; ++w) s += partials[t * 8 + w];
        m[b * SE_C + c0 + t] = s * (1.0f / SE_HW);
    }
    __syncthreads();

    // ---------------- per-batch sync (16 blocks, padded counter) -----------
    if (t == 0) {
        __hip_atomic_fetch_add(&ready[b * RDY_STRIDE], 1,
                               __ATOMIC_RELEASE, __HIP_MEMORY_SCOPE_AGENT);
        while (__hip_atomic_load(&ready[b * RDY_STRIDE],
                                 __ATOMIC_ACQUIRE, __HIP_MEMORY_SCOPE_AGENT) < CPB)
            __builtin_amdgcn_s_sleep(2);
    }
    __syncthreads();

    // ---------------- gate for this block's 16 channels --------------------
    if (t < SE_C / 4)
        m4_lds[t] = reinterpret_cast<const f32x4*>(m + b * SE_C)[t];
    __syncthreads();

    const f32x4* W1v = reinterpret_cast<const f32x4*>(W1);
    const f32x4 mv = m4_lds[lane];
#pragma unroll
    for (int i = 0; i < 8; ++i) {            // wave w owns rows 8w..8w+7
        const int o = wave * 8 + i;
        f32x4 w4 = W1v[o * 64 + lane];
        float p = w4.x * mv.x;
        p = fmaf(w4.y, mv.y, p);
        p = fmaf(w4.z, mv.z, p);
        p = fmaf(w4.w, mv.w, p);
#pragma unroll
        for (int off = 1; off < 64; off <<= 1) p += __shfl_xor(p, off);
        if (lane == 0) s_lds[o] = fmaxf(p + b1[o], 0.0f);
    }
    __syncthreads();

#pragma unroll
    for (int i = 0; i < 2; ++i) {            // wave w owns channels 2w,2w+1
        const int cl = wave * 2 + i;
        const int c  = c0 + cl;
        float p = W2[c * SE_SQ + lane] * s_lds[lane];
#pragma unroll
        for (int off = 1; off < 64; off <<= 1) p += __shfl_xor(p, off);
        if (lane == 0) g_lds[cl] = hsig(p + b2[c]);
    }
    __syncthreads();

    // ---------------- Phase 2: scale + nt store ----------------------------
    // re-read units first (k=21..31: streamed last => still MRU in L3)
#pragma unroll
    for (int k = N_REG + N_LDS; k < VPT; ++k) {
        f32x4 v = xv[k * TPB + t];
        v *= g_lds[k >> 1];
        __builtin_nontemporal_store(v, &yv[k * TPB + t]);
    }
#pragma unroll
    for (int k = N_REG; k < N_REG + N_LDS; ++k) {
        f32x4 v = lds[(k - N_REG) * TPB + t];
        v *= g_lds[k >> 1];
        __builtin_nontemporal_store(v, &yv[k * TPB + t]);
    }
#define OUT_REG(k, r) { f32x4 v = r; v *= g_lds[(k) >> 1]; \
                        __builtin_nontemporal_store(v, &yv[(k)*TPB + t]); }
    OUT_REG( 0, r0)  OUT_REG( 1, r1)  OUT_REG( 2, r2)  OUT_REG( 3, r3)
    OUT_REG( 4, r4)  OUT_REG( 5, r5)  OUT_REG( 6, r6)  OUT_REG( 7, r7)
    OUT_REG( 8, r8)  OUT_REG( 9, r9)  OUT_REG(10, r10) OUT_REG(11, r11)
}

extern "C" void kernel_launch(void* const* d_in, const int* in_sizes, int n_in,
                              void* d_out, int out_size, void* d_ws, size_t ws_size,
                              hipStream_t stream) {
    const float* x  = (const float*)d_in[0];
    const float* W1 = (const float*)d_in[1];
    const float* b1 = (const float*)d_in[2];
    const float* W2 = (const float*)d_in[3];
    const float* b2 = (const float*)d_in[4];
    float* y = (float*)d_out;

    float* m     = (float*)d_ws;
    int*   ready = (int*)(m + SE_B * SE_C);

    hipMemsetAsync(ready, 0, SE_B * RDY_STRIDE * sizeof(int), stream);
    se_fused_kernel<<<SE_B * (SE_C / CPB), TPB, 0, stream>>>(
        x, W1, b1, W2, b2, m, ready, y);
}

// Round 10
// 121.957 us; speedup vs baseline: 1.0109x; 1.0109x over previous
//
#include <hip/hip_runtime.h>

// SqueezeExcitation: x[32,256,64,64] f32, W1[64,256], b1[64], W2[256,64], b2[256]
// y = x * hardsigmoid( relu( mean_hw(x) @ W1^T + b1 ) @ W2^T + b2 )
// SINGLE kernel, one HBM pass + L3-hot re-read. 512 blocks x 512 thr, 2/CU.
// Block owns (batch, 16ch) = 256 KiB = 32 f32x4/thread:
//   9 units in LDS (72 KiB) + 23 units RE-READ from cache in phase 2.
// NO register-held units: r7/r8/r9 proved the allocator pins itself to the
// 64-VGPR bucket and will sink (r8) or spill (r9) anything held across the
// sync. r9 datum: within-kernel re-read after streaming is ~75-90% L3-hot
// (44MB re-read cost only ~12MB FETCH) — so re-read is CHEAP, holding is not.
// Phase 2 consumes re-read units first (streamed last = MRU; y-eviction eats
// the never-re-read LDS units at the LRU end first).
// r7 lesson: no cross-lane ops in the load stream (deferred reductions).
// r2 lesson: padded per-batch counters (16 adds each, zero contention).

#define SE_B  32
#define SE_C  256
#define SE_SQ 64
#define SE_HW 4096
#define CPB   16
#define TPB   512
#define VPT   32
#define N_LDS 9
#define RDY_STRIDE 32

typedef float f32x4 __attribute__((ext_vector_type(4)));

__device__ __forceinline__ float hsig(float v) {
    return fminf(fmaxf(v * (1.0f / 6.0f) + 0.5f, 0.0f), 1.0f);
}

__global__ __launch_bounds__(TPB, 4) void se_fused_kernel(
    const float* __restrict__ x,
    const float* __restrict__ W1, const float* __restrict__ b1,
    const float* __restrict__ W2, const float* __restrict__ b2,
    float* __restrict__ m, int* __restrict__ ready,
    float* __restrict__ y) {
    const int blk  = blockIdx.x;
    const int b    = blk >> 4;
    const int c0   = (blk & 15) * CPB;
    const int t    = threadIdx.x;
    const int wave = t >> 6;
    const int lane = t & 63;

    __shared__ f32x4 lds[N_LDS * TPB];      // 72 KiB
    __shared__ float partials[CPB * 8];
    __shared__ f32x4 m4_lds[SE_C / 4];
    __shared__ float s_lds[SE_SQ];
    __shared__ float g_lds[CPB];

    const size_t base = ((size_t)b * SE_C + c0) * (SE_HW / 4);
    const f32x4* xv = reinterpret_cast<const f32x4*>(x) + base;
    f32x4*       yv = reinterpret_cast<f32x4*>(y)       + base;

    // ---------------- Phase 1: stream once; deferred accumulators ----------
    // fully unrolled => acc[] indices are compile-time => stays in VGPRs
    float acc[CPB] = {0};
#pragma unroll
    for (int k = 0; k < VPT; ++k) {
        f32x4 v = xv[k * TPB + t];
        if (k < N_LDS) lds[k * TPB + t] = v;
        acc[k >> 1] += (v.x + v.y) + (v.z + v.w);
    }

    // reductions once, after the whole stream (r7 lesson)
#pragma unroll
    for (int j = 0; j < CPB; ++j) {
        float p = acc[j];
#pragma unroll
        for (int off = 1; off < 64; off <<= 1) p += __shfl_xor(p, off);
        if (lane == 0) partials[j * 8 + wave] = p;
    }
    __syncthreads();

    if (t < CPB) {
        float s = 0.0f;
#pragma unroll
        for (int w = 0; w < 8; ++w) s += partials[t * 8 + w];
        m[b * SE_C + c0 + t] = s * (1.0f / SE_HW);
    }
    __syncthreads();

    // ---------------- per-batch sync (16 blocks, padded counter) -----------
    if (t == 0) {
        __hip_atomic_fetch_add(&ready[b * RDY_STRIDE], 1,
                               __ATOMIC_RELEASE, __HIP_MEMORY_SCOPE_AGENT);
        while (__hip_atomic_load(&ready[b * RDY_STRIDE],
                                 __ATOMIC_ACQUIRE, __HIP_MEMORY_SCOPE_AGENT) < CPB)
            __builtin_amdgcn_s_sleep(2);
    }
    __syncthreads();

    // ---------------- gate for this block's 16 channels --------------------
    if (t < SE_C / 4)
        m4_lds[t] = reinterpret_cast<const f32x4*>(m + b * SE_C)[t];
    __syncthreads();

    const f32x4* W1v = reinterpret_cast<const f32x4*>(W1);
    const f32x4 mv = m4_lds[lane];
#pragma unroll
    for (int i = 0; i < 8; ++i) {            // wave w owns rows 8w..8w+7
        const int o = wave * 8 + i;
        f32x4 w4 = W1v[o * 64 + lane];       // coalesced row read
        float p = w4.x * mv.x;
        p = fmaf(w4.y, mv.y, p);
        p = fmaf(w4.z, mv.z, p);
        p = fmaf(w4.w, mv.w, p);
#pragma unroll
        for (int off = 1; off < 64; off <<= 1) p += __shfl_xor(p, off);
        if (lane == 0) s_lds[o] = fmaxf(p + b1[o], 0.0f);
    }
    __syncthreads();

#pragma unroll
    for (int i = 0; i < 2; ++i) {            // wave w owns channels 2w,2w+1
        const int cl = wave * 2 + i;
        const int c  = c0 + cl;
        float p = W2[c * SE_SQ + lane] * s_lds[lane];
#pragma unroll
        for (int off = 1; off < 64; off <<= 1) p += __shfl_xor(p, off);
        if (lane == 0) g_lds[cl] = hsig(p + b2[c]);
    }
    __syncthreads();

    // ---------------- Phase 2: scale + nt store ----------------------------
    // re-read units first (k=9..31: streamed later => closer to MRU)
#pragma unroll
    for (int k = N_LDS; k < VPT; ++k) {
        f32x4 v = xv[k * TPB + t];
        v *= g_lds[k >> 1];
        __builtin_nontemporal_store(v, &yv[k * TPB + t]);
    }
#pragma unroll
    for (int k = 0; k < N_LDS; ++k) {
        f32x4 v = lds[k * TPB + t];
        v *= g_lds[k >> 1];
        __builtin_nontemporal_store(v, &yv[k * TPB + t]);
    }
}

extern "C" void kernel_launch(void* const* d_in, const int* in_sizes, int n_in,
                              void* d_out, int out_size, void* d_ws, size_t ws_size,
                              hipStream_t stream) {
    const float* x  = (const float*)d_in[0];
    const float* W1 = (const float*)d_in[1];
    const float* b1 = (const float*)d_in[2];
    const float* W2 = (const float*)d_in[3];
    const float* b2 = (const float*)d_in[4];
    float* y = (float*)d_out;

    float* m     = (float*)d_ws;
    int*   ready = (int*)(m + SE_B * SE_C);

    hipMemsetAsync(ready, 0, SE_B * RDY_STRIDE * sizeof(int), stream);
    se_fused_kernel<<<SE_B * (SE_C / CPB), TPB, 0, stream>>>(
        x, W1, b1, W2, b2, m, ready, y);
}

// Round 11
// 69.044 us; speedup vs baseline: 1.7857x; 1.7664x over previous
//
#include <hip/hip_runtime.h>

// SqueezeExcitation: x[32,256,64,64] f32, W1[64,256], b1[64], W2[256,64], b2[256]
// y = x * hardsigmoid( relu( mean_hw(x) @ W1^T + b1 ) @ W2^T + b2 )
// conv1x1 linear => mean-then-matvec == matvec-then-mean. TWO kernels:
//   K1: per-(b,c) spatial mean m[b,c]                    (reads x, 128 MiB)
//   K2: fat blocks (1024 thr, batch x 16-channel chunk): redundant per-block
//       gate (coalesced W1/W2), then y = x*g with nontemporal stores.
// FINAL (reverted to round-6 best, 69.4 us). Experiment ledger:
//   r2: cross-block atomics on shared lines: 8192 contended RMW ~50ns each
//       => +375us. NEVER on the critical path.
//   r4: per-block redundant gate w/ uncoalesced W1 reads => L1-gather-bound
//       (4x payload overhead). Redundant work must be coalesced AND small.
//   r6: reverse-order re-read (LRU theory) => null; L3 x-residency ~50% is
//       structural (x + y = 256 MiB == L3 capacity; nt stores don't help).
//   r7-r10: one-pass persistent kernel (regs/LDS/cache mix + device-wide
//       phase sync): 102-123us. Allocator sinks (r8) or spills (r9) values
//       held across the sync; phase convoy caps HBM at ~2.5 TB/s. Dead end.
// Decomposition: K1 21us (read @ 6.2 TB/s ceiling) + ~2us boundary +
// K2 47us (256 MiB mixed r/w @ ~5.4 TB/s) = ~8% above composite of
// measured ceilings (copy 6.3 TB/s, fill 7.1 TB/s).

#define SE_B  32
#define SE_C  256
#define SE_SQ 64
#define SE_HW 4096   // 64*64
#define CHUNK 16     // channels per fused block

typedef float f32x4 __attribute__((ext_vector_type(4)));

__device__ __forceinline__ float hsig(float v) {
    return fminf(fmaxf(v * (1.0f / 6.0f) + 0.5f, 0.0f), 1.0f);
}

// ---------------- Kernel 1: per-(b,c) spatial mean --------------------------
__global__ __launch_bounds__(256) void se_mean_kernel(
    const float* __restrict__ x, float* __restrict__ m) {
    const int bc = blockIdx.x;                       // [0, B*C)
    const int t  = threadIdx.x;
    const f32x4* xv = reinterpret_cast<const f32x4*>(x) + (size_t)bc * (SE_HW / 4);

    float s = 0.0f;
#pragma unroll
    for (int k = 0; k < 4; ++k) {
        f32x4 v = xv[t + 256 * k];
        s += (v.x + v.y) + (v.z + v.w);
    }
#pragma unroll
    for (int off = 32; off > 0; off >>= 1) s += __shfl_down(s, off);

    __shared__ float wsum[4];
    if ((t & 63) == 0) wsum[t >> 6] = s;
    __syncthreads();
    if (t == 0) m[bc] = (wsum[0] + wsum[1] + wsum[2] + wsum[3]) * (1.0f / SE_HW);
}

// ---------------- Kernel 2: fused gate + scale (fat blocks, reversed) -------
// grid = 32 batches * 16 chunks = 512 blocks of 1024 threads (16 waves).
__global__ __launch_bounds__(1024, 8) void se_gate_scale_kernel(
    const float* __restrict__ x, const float* __restrict__ m,
    const float* __restrict__ W1, const float* __restrict__ b1,
    const float* __restrict__ W2, const float* __restrict__ b2,
    float* __restrict__ y) {
    // reverse traversal: first-dispatched blocks take the HIGHEST addresses
    const int blk   = (SE_B * (SE_C / CHUNK) - 1) - blockIdx.x;
    const int b     = blk >> 4;
    const int chunk = blk & 15;
    const int c0    = chunk * CHUNK;
    const int t     = threadIdx.x;
    const int wave  = t >> 6;            // 0..15
    const int lane  = t & 63;

    __shared__ f32x4 m4_lds[SE_C / 4];   // m[b,:] as 64 float4
    __shared__ float s_lds[SE_SQ];
    __shared__ float g_lds[CHUNK];

    // ---- stage m[b,:] (1 KiB, coalesced) ----------------------------------
    if (t < SE_C / 4)
        m4_lds[t] = reinterpret_cast<const f32x4*>(m + b * SE_C)[t];
    __syncthreads();

    // ---- s[o] = relu(b1[o] + W1[o,:] . m[b,:]), wave w owns o = 4w..4w+3 --
    const f32x4* W1v = reinterpret_cast<const f32x4*>(W1);
    const f32x4 mv = m4_lds[lane];
#pragma unroll
    for (int i = 0; i < 4; ++i) {
        const int o = wave * 4 + i;
        f32x4 w4 = W1v[o * 64 + lane];               // coalesced: whole row/wave
        float p = w4.x * mv.x;
        p = fmaf(w4.y, mv.y, p);
        p = fmaf(w4.z, mv.z, p);
        p = fmaf(w4.w, mv.w, p);
#pragma unroll
        for (int off = 1; off < 64; off <<= 1) p += __shfl_xor(p, off);
        if (lane == 0) s_lds[o] = fmaxf(p + b1[o], 0.0f);
    }
    __syncthreads();

    // ---- gate for channel c0+wave (wave j owns channel j of the chunk) ----
    {
        const int c = c0 + wave;                     // CHUNK == 16 waves
        float p = W2[c * SE_SQ + lane] * s_lds[lane];
#pragma unroll
        for (int off = 1; off < 64; off <<= 1) p += __shfl_xor(p, off);
        if (lane == 0) g_lds[wave] = hsig(p + b2[c]);
    }
    __syncthreads();

    // ---- stream: y = x * g, one 16 KiB channel per round, high->low -------
    const size_t base = ((size_t)b * SE_C + c0) * (SE_HW / 4);
    const f32x4* xv = reinterpret_cast<const f32x4*>(x) + base;
    f32x4*       yv = reinterpret_cast<f32x4*>(y)       + base;
#pragma unroll 4
    for (int jj = 0; jj < CHUNK; ++jj) {
        const int j = CHUNK - 1 - jj;                // reversed within block too
        const float g = g_lds[j];
        f32x4 v = xv[j * (SE_HW / 4) + t];
        v *= g;
        __builtin_nontemporal_store(v, &yv[j * (SE_HW / 4) + t]);
    }
}

extern "C" void kernel_launch(void* const* d_in, const int* in_sizes, int n_in,
                              void* d_out, int out_size, void* d_ws, size_t ws_size,
                              hipStream_t stream) {
    const float* x  = (const float*)d_in[0];
    const float* W1 = (const float*)d_in[1];
    const float* b1 = (const float*)d_in[2];
    const float* W2 = (const float*)d_in[3];
    const float* b2 = (const float*)d_in[4];
    float* y = (float*)d_out;

    float* m = (float*)d_ws;               // B*C floats

    se_mean_kernel<<<SE_B * SE_C, 256, 0, stream>>>(x, m);
    se_gate_scale_kernel<<<SE_B * (SE_C / CHUNK), 1024, 0, stream>>>(
        x, m, W1, b1, W2, b2, y);
}